// Round 1
// baseline (465.097 us; speedup 1.0000x reference)
//
#include <hip/hip_runtime.h>

// BlockCirculantLinear via frequency domain:
//   out[s, o*128+t] = ifft_t( sum_j fft(x_d[s,j,:]) * conj(fft(W[o,j,:])) )
// Stages: K1: DFT of x-blocks (MFMA GEMM vs cos/sin basis) -> X[f][s][jc] bf16
//         K2: per-frequency real-ified GEMM over jc (K=128) into LDS Y, then
//             inverse-DFT GEMM (K=160, zero-padded) -> out fp32. No Y in HBM.

typedef __bf16 bf16;
typedef __bf16 bf16x8 __attribute__((ext_vector_type(8)));
typedef float f32x4 __attribute__((ext_vector_type(4)));

#define PI_F 3.14159265358979323846f

// ws layout (bytes)
#define WS_B1   0u          // [192 fc][128 t] bf16 = 49152
#define WS_B2T  49152u      // [128 t][160 fc] bf16 = 40960
#define WS_WMAT 90112u      // [65 f][128 oc][128 jc] bf16 = 2129920
#define WS_X    2220032u    // [65 f][4096 s][128 jc] bf16 = 68157440

__device__ __forceinline__ unsigned int pack_bf2(float a, float b) {
    unsigned short ra = __builtin_bit_cast(unsigned short, (bf16)a);
    unsigned short rb = __builtin_bit_cast(unsigned short, (bf16)b);
    return (unsigned int)ra | ((unsigned int)rb << 16);
}

// ---------------- init: DFT bases ----------------
// B1[fc][t]: fc=2f+c; c=0 -> cos(2pi f t/128), c=1 -> -sin(...). Rows f>64 zero.
// B2T[t][fc]: inverse-rfft coefficients; fc>=130 zero (padding for K=160 loop).
__global__ __launch_bounds__(256) void init_basis(bf16* __restrict__ B1,
                                                  bf16* __restrict__ B2T) {
    int gid = blockIdx.x * 256 + threadIdx.x;
    if (gid < 192 * 128) {
        int fc = gid >> 7, t = gid & 127;
        int f = fc >> 1;
        float v = 0.f;
        if (f <= 64) {
            int a = (f * t) & 127;
            float ang = a * (PI_F / 64.f);
            v = (fc & 1) ? -__sinf(ang) : __cosf(ang);
        }
        B1[gid] = (bf16)v;
    }
    if (gid < 128 * 160) {
        int t = gid / 160, fc = gid % 160;
        int f = fc >> 1, c = fc & 1;
        float v = 0.f;
        if (f == 0) {
            v = c ? 0.f : (1.f / 128.f);
        } else if (f == 64) {
            v = c ? 0.f : ((t & 1) ? -1.f / 128.f : 1.f / 128.f);
        } else if (f < 64) {
            int a = (f * t) & 127;
            float ang = a * (PI_F / 64.f);
            v = c ? (-2.f / 128.f) * __sinf(ang) : (2.f / 128.f) * __cosf(ang);
        }
        B2T[gid] = (bf16)v;
    }
}

// ---------------- init: frequency-domain weights ----------------
// Wr[o,j,f] = sum_tau W cos, Wi = +sum_tau W sin  (== conj(fft(W)))
// Wmat[f][2o+0][2j+0]=Wr  [2o+0][2j+1]=-Wi  [2o+1][2j+0]=Wi  [2o+1][2j+1]=Wr
__global__ __launch_bounds__(256) void init_wmat(const float* __restrict__ W,
                                                 bf16* __restrict__ Wm) {
    __shared__ float ct[128], st[128];
    const int tid = threadIdx.x;
    if (tid < 128) {
        float ang = tid * (PI_F / 64.f);
        ct[tid] = __cosf(ang);
        st[tid] = __sinf(ang);
    }
    __syncthreads();
    int gid = blockIdx.x * 256 + tid;
    if (gid >= 65 * 4096) return;
    int f = gid >> 12;
    int rem = gid & 4095;
    int o = rem >> 6, j = rem & 63;
    const float* wp = W + (((o << 6) + j) << 7);
    float wr = 0.f, wi = 0.f;
    for (int tau = 0; tau < 128; tau++) {
        float w = wp[tau];
        int a = (f * tau) & 127;
        wr += w * ct[a];
        wi += w * st[a];
    }
    bf16* base = Wm + ((size_t)f * 128 + 2 * o) * 128 + 2 * j;
    base[0]   = (bf16)wr;
    base[1]   = (bf16)(-wi);
    base[128] = (bf16)wi;
    base[129] = (bf16)wr;
}

// ---------------- K1: DFT of x-blocks ----------------
// grid 512: blockIdx = s_tile(256) * 2 + j_half. block 256 (4 waves).
// Per 8-j round: stage x*D (fp32->bf16) to LDS, each wave computes 3 fc n-tiles
// (C[m=s16][n=fc16] per j), then XOR-1 lane exchange pairs (re,im) and stores
// 16B/lane to X[f][s][jc].
__global__ __launch_bounds__(256) void k1_dft(const float* __restrict__ x,
                                              const float* __restrict__ D,
                                              const bf16* __restrict__ B1,
                                              bf16* __restrict__ X) {
    __shared__ bf16 xs[8][16][136];
    const int tid = threadIdx.x;
    const int wave = tid >> 6, lane = tid & 63;
    const int q = lane >> 4, nl = lane & 15;
    const int s_t = blockIdx.x >> 1, jh = blockIdx.x & 1;
    const int s0 = s_t * 16;

    // constant B-fragments: wave's n-tiles nt = wave + 4*t (B1 rows fc>=130 are 0)
    bf16x8 bfrag[3][4];
#pragma unroll
    for (int t = 0; t < 3; t++) {
        int nt = wave + 4 * t;
#pragma unroll
        for (int kc = 0; kc < 4; kc++)
            bfrag[t][kc] = *(const bf16x8*)(B1 + (nt * 16 + nl) * 128 + kc * 32 + q * 8);
    }

    for (int grp = 0; grp < 4; grp++) {
        const int jb = jh * 32 + grp * 8;
        __syncthreads();
        {   // stage 8 j-blocks: 8*16*128 fp32 -> bf16 (apply diagonal D)
            const int jl = tid >> 5, ss = (tid >> 1) & 15, th = tid & 1;
            const float* xp = x + (size_t)(s0 + ss) * 8192 + (jb + jl) * 128 + th * 64;
            const float* Dp = D + (jb + jl) * 128 + th * 64;
            bf16* dst = &xs[jl][ss][th * 64];
#pragma unroll
            for (int u = 0; u < 8; u++) {
                float4 a  = *(const float4*)(xp + u * 8);
                float4 b  = *(const float4*)(xp + u * 8 + 4);
                float4 da = *(const float4*)(Dp + u * 8);
                float4 db = *(const float4*)(Dp + u * 8 + 4);
                bf16x8 o;
                o[0] = (bf16)(a.x * da.x); o[1] = (bf16)(a.y * da.y);
                o[2] = (bf16)(a.z * da.z); o[3] = (bf16)(a.w * da.w);
                o[4] = (bf16)(b.x * db.x); o[5] = (bf16)(b.y * db.y);
                o[6] = (bf16)(b.z * db.z); o[7] = (bf16)(b.w * db.w);
                *(bf16x8*)(dst + u * 8) = o;
            }
        }
        __syncthreads();

        f32x4 acc[3][8];
        const f32x4 zero = {0.f, 0.f, 0.f, 0.f};
#pragma unroll
        for (int t = 0; t < 3; t++)
#pragma unroll
            for (int j = 0; j < 8; j++) acc[t][j] = zero;

#pragma unroll
        for (int j = 0; j < 8; j++) {
#pragma unroll
            for (int kc = 0; kc < 4; kc++) {
                bf16x8 a = *(const bf16x8*)&xs[j][nl][kc * 32 + q * 8];
#pragma unroll
                for (int t = 0; t < 3; t++)
                    acc[t][j] = __builtin_amdgcn_mfma_f32_16x16x32_bf16(
                        a, bfrag[t][kc], acc[t][j], 0, 0, 0);
            }
        }

        // register transpose + store: lane pair (fc even/odd) = (re, im)
        const int par = lane & 1;
#pragma unroll
        for (int t = 0; t < 3; t++) {
            const int fc = (wave + 4 * t) * 16 + nl;
            const int fpr = fc >> 1;
            const bool wr = (fc < 130);
#pragma unroll
            for (int r = 0; r < 4; r++) {
                float sh[8];
#pragma unroll
                for (int j = 0; j < 8; j++)
                    sh[j] = __shfl_xor(acc[t][j][r], 1);
                unsigned int d0, d1, d2, d3;
                if (!par) {
                    d0 = pack_bf2(acc[t][0][r], sh[0]);
                    d1 = pack_bf2(acc[t][1][r], sh[1]);
                    d2 = pack_bf2(acc[t][2][r], sh[2]);
                    d3 = pack_bf2(acc[t][3][r], sh[3]);
                } else {
                    d0 = pack_bf2(sh[4], acc[t][4][r]);
                    d1 = pack_bf2(sh[5], acc[t][5][r]);
                    d2 = pack_bf2(sh[6], acc[t][6][r]);
                    d3 = pack_bf2(sh[7], acc[t][7][r]);
                }
                if (wr) {
                    char* p = (char*)X + ((size_t)fpr * 4096 + s0 + q * 4 + r) * 256
                              + jb * 4 + par * 16;
                    *(uint4*)p = make_uint4(d0, d1, d2, d3);
                }
            }
        }
    }
}

// ---------------- K2: per-frequency contraction + inverse DFT ----------------
// grid 2048: blockIdx = s_tile(256)*8 + o_tile(8). block 256 (4 waves).
// Phase A: wave w handles f = grp*4+w; C[m=oc16][n=s16] = Wmat[f] * X[f]^T,
//          frags straight from global (L2/LLC-hot), scatter into LDS Y[o][s][fc].
// Phase B: per (o, t-tile): out[s,t] = Y[s][o][:] * B2T (K=160; B2T rows>=130 = 0).
__global__ __launch_bounds__(256) void k2_gemm(const bf16* __restrict__ X,
                                               const bf16* __restrict__ Wmat,
                                               const bf16* __restrict__ B2T,
                                               float* __restrict__ out) {
    __shared__ bf16 ybuf[8 * 16 * 136 + 32];  // [o][s][fc136] + overrun pad
    const int tid = threadIdx.x;
    const int wave = tid >> 6, lane = tid & 63;
    const int q = lane >> 4, nl = lane & 15;
    const int s_t = blockIdx.x >> 3, o_t = blockIdx.x & 7;
    const int s0 = s_t * 16;

    {   // zero (covers fc 130..135 pad + masked freqs)
        unsigned int* yz = (unsigned int*)ybuf;
        for (int i = tid; i < (8 * 16 * 136 + 32) / 2; i += 256) yz[i] = 0u;
    }
    __syncthreads();

    for (int grp = 0; grp < 17; grp++) {
        const int f = grp * 4 + wave;
        if (f < 65) {
            f32x4 acc = {0.f, 0.f, 0.f, 0.f};
#pragma unroll
            for (int kc = 0; kc < 4; kc++) {
                bf16x8 a = *(const bf16x8*)(Wmat + ((size_t)f * 128 + o_t * 16 + nl) * 128
                                            + kc * 32 + q * 8);
                bf16x8 b = *(const bf16x8*)(X + ((size_t)f * 4096 + s0 + nl) * 128
                                            + kc * 32 + q * 8);
                acc = __builtin_amdgcn_mfma_f32_16x16x32_bf16(a, b, acc, 0, 0, 0);
            }
#pragma unroll
            for (int r = 0; r < 4; r++) {
                int oc = q * 4 + r;
                int o = oc >> 1, c = oc & 1;
                ybuf[(o * 16 + nl) * 136 + 2 * f + c] = (bf16)acc[r];
            }
        }
    }
    __syncthreads();

    for (int p = wave; p < 64; p += 4) {
        const int o = p >> 3, nt = p & 7;
        f32x4 acc = {0.f, 0.f, 0.f, 0.f};
#pragma unroll
        for (int kc = 0; kc < 5; kc++) {
            bf16x8 a = *(const bf16x8*)&ybuf[(o * 16 + nl) * 136 + kc * 32 + q * 8];
            bf16x8 b = *(const bf16x8*)(B2T + (nt * 16 + nl) * 160 + kc * 32 + q * 8);
            acc = __builtin_amdgcn_mfma_f32_16x16x32_bf16(a, b, acc, 0, 0, 0);
        }
        float* op = out + (size_t)(s0 + q * 4) * 8192 + (o_t * 8 + o) * 128 + nt * 16 + nl;
#pragma unroll
        for (int r = 0; r < 4; r++)
            op[(size_t)r * 8192] = acc[r];
    }
}

extern "C" void kernel_launch(void* const* d_in, const int* in_sizes, int n_in,
                              void* d_out, int out_size, void* d_ws, size_t ws_size,
                              hipStream_t stream) {
    const float* x = (const float*)d_in[0];
    const float* W = (const float*)d_in[1];
    const float* D = (const float*)d_in[2];
    float* out = (float*)d_out;
    char* ws = (char*)d_ws;
    bf16* B1  = (bf16*)(ws + WS_B1);
    bf16* B2T = (bf16*)(ws + WS_B2T);
    bf16* Wm  = (bf16*)(ws + WS_WMAT);
    bf16* X   = (bf16*)(ws + WS_X);

    hipLaunchKernelGGL(init_basis, dim3(96), dim3(256), 0, stream, B1, B2T);
    hipLaunchKernelGGL(init_wmat, dim3(1040), dim3(256), 0, stream, W, Wm);
    hipLaunchKernelGGL(k1_dft, dim3(512), dim3(256), 0, stream, x, D, B1, X);
    hipLaunchKernelGGL(k2_gemm, dim3(2048), dim3(256), 0, stream, X, Wm, B2T, out);
}